// Round 5
// baseline (175.534 us; speedup 1.0000x reference)
//
#include <hip/hip_runtime.h>

typedef unsigned short ushort_t;
typedef ushort_t u16x8 __attribute__((ext_vector_type(8)));
typedef __bf16 bf16x8 __attribute__((ext_vector_type(8)));
typedef float f32x4 __attribute__((ext_vector_type(4)));

#define DET 736
#define NPAD 768
#define NT 23     // K-steps: 736 / 32
#define RB 48     // A-rows per block
#define LDW 744   // padded LDS row stride (bf16): 1488 B, 16B-aligned, bank-even

// Bt[n][k] = w[k] * f[k - n + 735]   (cosine pre-weight folded into the filter
// matrix: OUT = (X . w) * W  ==  X * (diag(w) W)).  Rows n>=736 are zero pad.
__global__ void prep_bt(const float* __restrict__ filt, ushort_t* __restrict__ Bt) {
    int idx = blockIdx.x * blockDim.x + threadIdx.x;
    if (idx >= NPAD * DET) return;
    int n = idx / DET;
    int k = idx - n * DET;
    float w = 0.05f * cosf(((float)k - 367.5f) * 0.001f);
    float v = (n < DET) ? filt[k - n + (DET - 1)] * w : 0.0f;  // index in [0,1471)
    Bt[idx] = __builtin_bit_cast(ushort_t, (__bf16)v);
}

// OUT[M x 736] = sino[M x 736] * W'[736 x 736]
// A-STATIONARY structure: stage the block's whole A panel (48 x 736 bf16) into
// LDS once, ONE barrier, then a barrier-free K-loop: A frags from LDS, B frags
// global->reg (L2-resident 1.1 MB Toeplitz), 1-iter software prefetch.
// No per-iteration vmcnt(0) drain / barrier chain -- that chain was the 42 us
// floor of all previous variants.
__global__ __launch_bounds__(256, 2) void gemm_as(
    const float* __restrict__ A,      // M x DET fp32 sinogram
    const ushort_t* __restrict__ Bt,  // NPAD x DET bf16 bits
    float* __restrict__ C, int M)
{
    __shared__ ushort_t As[RB * LDW];   // 71,424 B -> 2 blocks/CU

    const int tid  = threadIdx.x;
    const int lane = tid & 63;
    const int warp = tid >> 6;   // 0..3 -> N-strip of 192 cols
    const int quad = lane >> 4;  // 0..3
    const int l16  = lane & 15;

    const size_t row_a0 = (size_t)blockIdx.x * RB;

    // ---- stage A once: 48 rows x 92 chunks of 8 fp32 -> bf16, padded rows ----
    for (int c = tid; c < RB * 92; c += 256) {
        int row  = c / 92;
        int part = c - row * 92;
        const float* g = A + (row_a0 + row) * DET + part * 8;
        f32x4 lo = *(const f32x4*)g;
        f32x4 hi = *(const f32x4*)(g + 4);
        u16x8 v;
#pragma unroll
        for (int e = 0; e < 4; ++e) {
            v[e]     = __builtin_bit_cast(ushort_t, (__bf16)lo[e]);
            v[e + 4] = __builtin_bit_cast(ushort_t, (__bf16)hi[e]);
        }
        *(u16x8*)(As + row * LDW + part * 8) = v;
    }
    __syncthreads();   // the ONLY barrier

    // ---- barrier-free compute: wave strip = all 48 rows x 192 cols ----
    const int n0 = warp * 192;

    for (int nc = 0; nc < 3; ++nc) {
        const int nb = n0 + nc * 64;

        f32x4 acc[3][4];
#pragma unroll
        for (int mi = 0; mi < 3; ++mi)
#pragma unroll
            for (int ni = 0; ni < 4; ++ni)
                acc[mi][ni] = (f32x4){0.f, 0.f, 0.f, 0.f};

        const ushort_t* bp[4];
#pragma unroll
        for (int ni = 0; ni < 4; ++ni)
            bp[ni] = Bt + (size_t)(nb + ni * 16 + l16) * DET + quad * 8;

        // prologue: frags for t=0
        u16x8 bcur[4], acur[3];
#pragma unroll
        for (int ni = 0; ni < 4; ++ni)
            bcur[ni] = *(const u16x8*)(bp[ni]);
#pragma unroll
        for (int mi = 0; mi < 3; ++mi)
            acur[mi] = *(const u16x8*)(As + (mi * 16 + l16) * LDW + quad * 8);

#pragma unroll
        for (int t = 0; t < NT; ++t) {
            u16x8 bnx[4], anx[3];
            if (t + 1 < NT) {
                const int ko = (t + 1) * 32;
#pragma unroll
                for (int ni = 0; ni < 4; ++ni)
                    bnx[ni] = *(const u16x8*)(bp[ni] + ko);
#pragma unroll
                for (int mi = 0; mi < 3; ++mi)
                    anx[mi] = *(const u16x8*)(As + (mi * 16 + l16) * LDW + ko + quad * 8);
            }
#pragma unroll
            for (int mi = 0; mi < 3; ++mi)
#pragma unroll
                for (int ni = 0; ni < 4; ++ni)
                    acc[mi][ni] = __builtin_amdgcn_mfma_f32_16x16x32_bf16(
                        __builtin_bit_cast(bf16x8, acur[mi]),
                        __builtin_bit_cast(bf16x8, bcur[ni]),
                        acc[mi][ni], 0, 0, 0);
            if (t + 1 < NT) {
#pragma unroll
                for (int ni = 0; ni < 4; ++ni) bcur[ni] = bnx[ni];
#pragma unroll
                for (int mi = 0; mi < 3; ++mi) acur[mi] = anx[mi];
            }
        }

        // epilogue: C/D layout col=lane&15, row=quad*4+reg [verified mapping]
#pragma unroll
        for (int mi = 0; mi < 3; ++mi) {
#pragma unroll
            for (int ni = 0; ni < 4; ++ni) {
                int colg = nb + ni * 16 + l16;
                if (colg < DET) {
#pragma unroll
                    for (int r = 0; r < 4; ++r) {
                        size_t rowg = row_a0 + mi * 16 + quad * 4 + r;
                        C[rowg * DET + colg] = acc[mi][ni][r];
                    }
                }
            }
        }
    }
}

extern "C" void kernel_launch(void* const* d_in, const int* in_sizes, int n_in,
                              void* d_out, int out_size, void* d_ws, size_t ws_size,
                              hipStream_t stream) {
    const float* sino = (const float*)d_in[0];
    const float* filt = (const float*)d_in[1];
    int total = in_sizes[0];     // 16*1*1152*736 = 13,565,952
    int M = total / DET;         // 18432

    ushort_t* Btb = (ushort_t*)d_ws;   // 768*736*2 = 1.08 MB
    float* out = (float*)d_out;

    prep_bt<<<(NPAD * DET + 255) / 256, 256, 0, stream>>>(filt, Btb);

    gemm_as<<<dim3(M / RB), 256, 0, stream>>>(sino, Btb, out, M);
}

// Round 6
// 138.622 us; speedup vs baseline: 1.2663x; 1.2663x over previous
//
#include <hip/hip_runtime.h>

typedef unsigned short ushort_t;
typedef ushort_t u16x8 __attribute__((ext_vector_type(8)));
typedef __bf16 bf16x8 __attribute__((ext_vector_type(8)));
typedef float f32x4 __attribute__((ext_vector_type(4)));

#define DET 736
#define NPAD 768
#define NT 23              // K-tiles of 32
#define NRB 1152           // M/16 row-blocks (M = 18432)
#define CPB (NT * 64)      // 1472 frag-chunks per 16-row block (or per 16-col block)

// ---------------------------------------------------------------------------
// Fragment-major layouts. A chunk = (blk16, t, lane) holds 8 contiguous elems:
//   A'[((rblk*NT + t)*64 + lane)*8 + e] = bf16( A[rblk*16 + (lane&15)]
//                                               [t*32 + (lane>>4)*8 + e] )
// identical scheme for B' over columns n. MFMA frag loads become 16B/lane
// CONTIGUOUS (the round-5 killer was 1472B-strided lane reads: 8x L2 ampl).
// ---------------------------------------------------------------------------

__global__ void prep_af(const float* __restrict__ sino, ushort_t* __restrict__ Af) {
    int c = blockIdx.x * blockDim.x + threadIdx.x;   // exact grid, no guard
    int rblk = c / CPB;
    int rem  = c - rblk * CPB;
    int t    = rem >> 6;
    int lane = rem & 63;
    int rr = lane & 15, quad = lane >> 4;
    const float* g = sino + (size_t)(rblk * 16 + rr) * DET + t * 32 + quad * 8;
    f32x4 lo = *(const f32x4*)g;
    f32x4 hi = *(const f32x4*)(g + 4);
    u16x8 v;
#pragma unroll
    for (int e = 0; e < 4; ++e) {
        v[e]     = __builtin_bit_cast(ushort_t, (__bf16)lo[e]);
        v[e + 4] = __builtin_bit_cast(ushort_t, (__bf16)hi[e]);
    }
    *(u16x8*)(Af + (size_t)c * 8) = v;
}

// B'[chunk(cb,t,lane)][e] = w(k) * h[k - n + 735],  n = cb*16 + (lane&15),
// k = t*32 + (lane>>4)*8 + e.  Cols 736..767 zero-padded. 48 cb x 1472 chunks.
__global__ void prep_bf(const float* __restrict__ filt, ushort_t* __restrict__ Bf) {
    int c = blockIdx.x * blockDim.x + threadIdx.x;   // 0..70655 exact
    int cb  = c / CPB;
    int rem = c - cb * CPB;
    int t    = rem >> 6;
    int lane = rem & 63;
    int cc = lane & 15, quad = lane >> 4;
    int n = cb * 16 + cc;
    u16x8 v;
#pragma unroll
    for (int e = 0; e < 8; ++e) {
        int k = t * 32 + quad * 8 + e;
        float w = 0.05f * cosf(((float)k - 367.5f) * 0.001f);
        float val = (n < DET) ? filt[k - n + (DET - 1)] * w : 0.0f;
        v[e] = __builtin_bit_cast(ushort_t, (__bf16)val);
    }
    *(u16x8*)(Bf + (size_t)c * 8) = v;
}

// OUT[M x 736] = sino * W'.  Frag-direct GEMM:
//  - 1024-thr block = 16 waves; wave = 64 rows x 64 cols; grid (18, 12).
//  - B strip (4 col-blocks x full K = 94 KB, frag-linear) staged to LDS ONCE
//    (single barrier); ds_read_b128 at lane*16 -> conflict-free.
//  - A frags global->reg, lane-contiguous 16B (coalesced); L3 absorbs the
//    12x cross-strip re-read (A' = 27 MB << 256 MB).
//  - K-loop: 4 global + 4 ds_read + 16 MFMA, zero barriers, zero vmcnt drains.
__global__ __launch_bounds__(1024, 4) void gemm_frag(
    const ushort_t* __restrict__ Af,
    const ushort_t* __restrict__ Bf,
    float* __restrict__ C)
{
    __shared__ ushort_t Bs[4 * CPB * 8];   // 47104 elems = 94208 B

    const int tid  = threadIdx.x;
    const int lane = tid & 63;
    const int wid  = tid >> 6;          // 0..15
    const int quad = lane >> 4;
    const int l16  = lane & 15;

    // stage B strip once (frag-linear copy, fully coalesced)
    const ushort_t* bsrc = Bf + (size_t)blockIdx.y * (4 * CPB * 8);
    for (int c = tid; c < 4 * CPB; c += 1024)
        *(u16x8*)(Bs + c * 8) = *(const u16x8*)(bsrc + (size_t)c * 8);
    __syncthreads();   // the only barrier

    const int rblk0 = blockIdx.x * 64 + wid * 4;   // 4 row-blocks per wave

    f32x4 acc[4][4];
#pragma unroll
    for (int i = 0; i < 4; ++i)
#pragma unroll
        for (int j = 0; j < 4; ++j)
            acc[i][j] = (f32x4){0.f, 0.f, 0.f, 0.f};

    const ushort_t* pA[4];
#pragma unroll
    for (int mi = 0; mi < 4; ++mi)
        pA[mi] = Af + ((size_t)(rblk0 + mi) * CPB + lane) * 8;
    const ushort_t* pB[4];
#pragma unroll
    for (int ni = 0; ni < 4; ++ni)
        pB[ni] = Bs + (ni * CPB + lane) * 8;

    for (int t = 0; t < NT; ++t) {
        u16x8 a[4], b[4];
#pragma unroll
        for (int mi = 0; mi < 4; ++mi)
            a[mi] = *(const u16x8*)(pA[mi] + t * 512);
#pragma unroll
        for (int ni = 0; ni < 4; ++ni)
            b[ni] = *(const u16x8*)(pB[ni] + t * 512);
#pragma unroll
        for (int mi = 0; mi < 4; ++mi)
#pragma unroll
            for (int ni = 0; ni < 4; ++ni)
                acc[mi][ni] = __builtin_amdgcn_mfma_f32_16x16x32_bf16(
                    __builtin_bit_cast(bf16x8, a[mi]),
                    __builtin_bit_cast(bf16x8, b[ni]),
                    acc[mi][ni], 0, 0, 0);
    }

    // epilogue: C/D layout col=lane&15, row=quad*4+reg [verified mapping]
    const int col0 = blockIdx.y * 64;
#pragma unroll
    for (int mi = 0; mi < 4; ++mi) {
#pragma unroll
        for (int ni = 0; ni < 4; ++ni) {
            int colg = col0 + ni * 16 + l16;
            if (colg < DET) {
#pragma unroll
                for (int r = 0; r < 4; ++r) {
                    size_t rowg = (size_t)(rblk0 + mi) * 16 + quad * 4 + r;
                    C[rowg * DET + colg] = acc[mi][ni][r];
                }
            }
        }
    }
}

extern "C" void kernel_launch(void* const* d_in, const int* in_sizes, int n_in,
                              void* d_out, int out_size, void* d_ws, size_t ws_size,
                              hipStream_t stream) {
    const float* sino = (const float*)d_in[0];
    const float* filt = (const float*)d_in[1];
    int total = in_sizes[0];     // 16*1*1152*736 = 13,565,952
    int M = total / DET;         // 18432 (= NRB*16, fixed by harness)

    ushort_t* Af = (ushort_t*)d_ws;                      // 27.1 MB frag-major A
    ushort_t* Bf = Af + (size_t)NRB * CPB * 8;           // +1.13 MB frag-major B
    float* out = (float*)d_out;

    prep_af<<<(NRB * CPB) / 256, 256, 0, stream>>>(sino, Af);
    prep_bf<<<(48 * CPB) / 256, 256, 0, stream>>>(filt, Bf);

    dim3 grid(M / 1024, NPAD / 64);   // 18 x 12 = 216 blocks, all co-resident
    gemm_frag<<<grid, 1024, 0, stream>>>(Af, Bf, out);
}